// Round 12
// baseline (328.231 us; speedup 1.0000x reference)
//
#include <hip/hip_runtime.h>
#include <stdint.h>

// CIN layers: Xn[b,h,d] = sum_{j,k} W[h,j,k] * X0[b,j,d] * Xi[b,k,d] + bias[h]
// y[d,h] = sum_k Xi*W (mfma_32x32x16, A rows m=b'*16+d, B cols=32h), then
// Xacc += x0[b,j,d]*y.
// R21 post-mortem: 296.5us total (best), fused 234.8 with occupancy 11.4% =
// 1 wave/SIMD. Per-SIMD pipe work (MFMA ~21us + VALU ~16us) is ~1/5 of the
// per-block wall: every dep gap (MFMA-latency->fma tail, ds_read->xsc, W
// vmcnt) is exposed with no co-resident wave to fill it.
// R22: 2 waves/SIMD via ONE 512-thread block (8 waves). launch_bounds(512,1)
// forces 2 waves/SIMD residency with a 256-reg cap (our demand ~170 -> no
// spill; note (256,2) caps at 128 per R11 = spill trap). Wave wv = (ht=wv&3,
// bp=wv>>2): the P-chain dimension moves onto waves; per-wave state drops
// (af 32, Xacc 16, w 64) while per-SIMD totals are unchanged. Co-resident
// waves interleave at issue granularity -- real TLP (R12-R14 added blocks,
// never co-issued waves per SIMD). W L2 traffic 2x (waves wv, wv+4 read same
// fragments) -- irrelevant at 2% HBM. Everything else = R21 (fused 3 layers,
// Xn via LDS XROW=130, f32 x0, j-major, W global->reg ping-pong, merged prep).

#define NB_F0 39
#define NB_H  128
#define NB_B  4096
#define XROW 130   // padded k-row stride (shorts) for Xa/Xb

typedef float f32x4  __attribute__((ext_vector_type(4)));
typedef float f32x16 __attribute__((ext_vector_type(16)));
typedef short s16x8  __attribute__((ext_vector_type(8)));

template <int N> struct IC { static constexpr int value = N; };

__device__ __forceinline__ unsigned short rne_bf16(float f) {
  union { float f; unsigned u; } v; v.f = f;
  return (unsigned short)((v.u + 0x7fffu + ((v.u >> 16) & 1u)) >> 16);
}

// Merged prep (one launch):
//  blocks [0, NB_B): X0 f32 [B][39][16] -> X0T bf16 [B][16][64] (k=j pad) and
//    X0f f32 [B][39][16] d-PERMUTED (pos<->d swap bits 2,3) so a lane's 8 x0
//    factors for MFMA regs r=0..7 (d=(r&3)+8*((r>>2)&1)+4L) are contiguous.
//  remaining blocks: W f32 [128][39*Fi] -> Wf bf16 fragment-linear:
//    Wf[(((j*4+t)*KC16+c)*64+lane)*8+i] = W[h=t*32+(lane&31)][j, k=c*16+
//    (lane>>5)*8+i] (0 if k>=Fi), for W0 (KC16=4) then W1, W2 (KC16=8).
__global__ void prep_all_kernel(const float* __restrict__ X0g,
                                unsigned short* __restrict__ X0T,
                                float* __restrict__ X0f,
                                const float* __restrict__ W0s,
                                unsigned short* __restrict__ Wf0,
                                const float* __restrict__ W1s,
                                unsigned short* __restrict__ Wf1,
                                const float* __restrict__ W2s,
                                unsigned short* __restrict__ Wf2) {
  const int t = threadIdx.x;
  int blk = blockIdx.x;
  if (blk < NB_B) {
    const int b = blk;
    {
      const int d  = t >> 4;
      const int k4 = (t & 15) << 2;
      unsigned short vv[4];
#pragma unroll
      for (int i = 0; i < 4; ++i) {
        const int k = k4 + i;
        vv[i] = (k < NB_F0)
                    ? rne_bf16(X0g[(size_t)b * (NB_F0 * 16) + k * 16 + d])
                    : (unsigned short)0;
      }
      ushort4 pk; pk.x = vv[0]; pk.y = vv[1]; pk.z = vv[2]; pk.w = vv[3];
      *(ushort4*)&X0T[((size_t)b * 16 + d) * 64 + k4] = pk;
    }
    for (int idx = t; idx < NB_F0 * 16; idx += 256) {
      const int j = idx >> 4, pos = idx & 15;
      const int d =
          (pos & 3) | (((pos >> 3) & 1) << 2) | (((pos >> 2) & 1) << 3);
      X0f[(size_t)b * (NB_F0 * 16) + idx] =
          X0g[(size_t)b * (NB_F0 * 16) + j * 16 + d];
    }
    return;
  }
  blk -= NB_B;
  constexpr int TW0  = NB_F0 * 4 * 4 * 512;   // KC16=4
  constexpr int TW12 = NB_F0 * 4 * 8 * 512;   // KC16=8
  constexpr int NB0  = TW0 / 256;
  constexpr int NB12 = TW12 / 256;
  const float* Wsrc; unsigned short* Wdst; int Fi, kshift, idx;
  if (blk < NB0) {
    Wsrc = W0s; Wdst = Wf0; Fi = 39;  kshift = 2; idx = blk * 256 + t;
  } else if (blk < NB0 + NB12) {
    Wsrc = W1s; Wdst = Wf1; Fi = 128; kshift = 3;
    idx = (blk - NB0) * 256 + t;
  } else {
    Wsrc = W2s; Wdst = Wf2; Fi = 128; kshift = 3;
    idx = (blk - NB0 - NB12) * 256 + t;
  }
  const int i    = idx & 7;
  const int lane = (idx >> 3) & 63;
  const int c    = (idx >> 9) & ((1 << kshift) - 1);
  const int jt   = idx >> (9 + kshift);
  const int tt   = jt & 3;
  const int j    = jt >> 2;
  const int h = tt * 32 + (lane & 31);
  const int k = c * 16 + ((lane >> 5) << 3) + i;
  unsigned short v = 0;
  if (k < Fi) v = rne_bf16(Wsrc[(size_t)h * (NB_F0 * Fi) + j * Fi + k]);
  Wdst[idx] = v;
}

__global__ __launch_bounds__(512, 1) void cin_fused(
    const unsigned short* __restrict__ Wf0,
    const unsigned short* __restrict__ Wf1,
    const unsigned short* __restrict__ Wf2,
    const unsigned short* __restrict__ X0T,  // [B][16][64] bf16 (k zero-pad)
    const float* __restrict__ X0f,           // [B][39][16] f32, d-permuted
    const float* __restrict__ bias0,
    const float* __restrict__ bias1,
    const float* __restrict__ bias2,
    float* __restrict__ outp)                // [B][384]
{
  __shared__ __attribute__((aligned(16))) float x0f[4 * NB_F0 * 16];
  __shared__ __attribute__((aligned(16))) unsigned short Xa[4 * 16 * XROW];
  __shared__ __attribute__((aligned(16))) unsigned short Xb[4 * 16 * XROW];

  const int tid  = threadIdx.x;
  const int lane = tid & 63;
  const int wv   = tid >> 6;        // 0..7
  const int ht   = wv & 3;          // h-tile: h = ht*32 + col
  const int bp   = wv >> 2;         // b-pair: b_local in {2bp, 2bp+1}
  const int L    = lane >> 5;       // k-half selector within a 16-chunk
  const int col  = lane & 31;       // A row m / B col
  const int bblk = blockIdx.x * 4;  // 4 b per block

  // ---- stage x0 factors (f32 d-permuted, flat coalesced copy) ----
  {
    const float* src = X0f + (size_t)bblk * (NB_F0 * 16);
    for (int c = tid; c < (4 * NB_F0 * 16) / 4; c += 512)
      *(f32x4*)&x0f[c * 4] = *(const f32x4*)&src[c * 4];
  }
  __syncthreads();   // publish x0f

  const int x0base = L * 8;

  // One CIN layer. KC16 = K-chunks (4 for Fi=64-pad, 8 for Fi=128);
  // AST = Xi A-fragment row stride in shorts (64 global X0T, XROW LDS).
  // This wave computes its (ht, bp) tile: 2 b x 32 h, single MFMA chain.
  auto layer = [&](auto kc, auto ast, const unsigned short* __restrict__ Wl,
                   const unsigned short* af_base, const float* __restrict__ bv,
                   float* __restrict__ op, unsigned short* xn) {
    constexpr int KC16 = decltype(kc)::value;
    constexpr int AST  = decltype(ast)::value;

    // ---- Xi A-fragments: rows m = (b_local = 2bp + (col>>4)) x 16 d ----
    s16x8 af[KC16];
    {
      const unsigned short* base = af_base +
          (size_t)(2 * bp + (col >> 4)) * (16 * AST) + (col & 15) * AST + L * 8;
#pragma unroll
      for (int c = 0; c < KC16; ++c) af[c] = *(const s16x8*)(base + c * 16);
    }

    f32x16 Xacc, kZero;
#pragma unroll
    for (int r = 0; r < 16; ++r) kZero[r] = 0.f;
    Xacc = kZero;

    // ---- W fragments straight from global (L2-hot) into registers ----
    const s16x8* __restrict__ W8 = (const s16x8*)Wl;
    auto wload = [&](int j, s16x8 (&w)[KC16]) {
      const s16x8* p = W8 + ((size_t)(j * 4 + ht) * KC16) * 64 + lane;
#pragma unroll
      for (int c = 0; c < KC16; ++c) w[c] = p[c * 64];
    };

    auto compute = [&](int s, const s16x8 (&w)[KC16]) {
      f32x16 y = __builtin_amdgcn_mfma_f32_32x32x16_bf16(af[0], w[0],
                                                         kZero, 0, 0, 0);
#pragma unroll
      for (int c = 1; c < KC16; ++c)
        y = __builtin_amdgcn_mfma_f32_32x32x16_bf16(af[c], w[c], y, 0, 0, 0);
      // x0 scale: regs 0-7 <- b'=2bp (this lane's L 8-run), 8-15 <- 2bp+1.
      // f32 factors: broadcast ds_read_b128 x4, zero unpack VALU.
      const float* xr0 = &x0f[x0base + (2 * bp + 0) * (NB_F0 * 16) + s * 16];
      const float* xr1 = &x0f[x0base + (2 * bp + 1) * (NB_F0 * 16) + s * 16];
      const f32x4 a0 = *(const f32x4*)(xr0);
      const f32x4 a1 = *(const f32x4*)(xr0 + 4);
      const f32x4 a2 = *(const f32x4*)(xr1);
      const f32x4 a3 = *(const f32x4*)(xr1 + 4);
      f32x16 xsc;
#pragma unroll
      for (int i = 0; i < 4; ++i) {
        xsc[i]      = a0[i];
        xsc[4 + i]  = a1[i];
        xsc[8 + i]  = a2[i];
        xsc[12 + i] = a3[i];
      }
      Xacc = __builtin_elementwise_fma(xsc, y, Xacc);
    };

    // ---- barrier-free main loop: W reg ping-pong, 1-stage prefetch ----
    s16x8 wA[KC16], wB[KC16];
    wload(0, wA);
    wload(1, wB);
    int s = 0;
    for (; s + 2 <= NB_F0; s += 2) {
      compute(s, wA);
      wload(s + 2 < NB_F0 ? s + 2 : 0, wA);   // reissue post-use (reg WAR ok)
      compute(s + 1, wB);
      if (s + 3 < NB_F0) wload(s + 3, wB);
    }
    if (s < NB_F0) compute(s, wA);   // odd tail (S=39)

    // ---- epilogue: sums to global; Xn to LDS in A-fragment layout ----
    const float bias_v = bv[ht * 32 + col];
#pragma unroll
    for (int bh = 0; bh < 2; ++bh) {
      const int bl = 2 * bp + bh;
      float v[8];
#pragma unroll
      for (int m = 0; m < 8; ++m) v[m] = Xacc[bh * 8 + m] + bias_v;
      if (xn) {
#pragma unroll
        for (int m = 0; m < 8; ++m) {
          const int d = (m & 3) + 8 * ((m >> 2) & 1) + 4 * L;
          xn[(bl * 16 + d) * XROW + ht * 32 + col] = rne_bf16(v[m]);
        }
      }
      float tot = ((v[0] + v[1]) + (v[2] + v[3])) +
                  ((v[4] + v[5]) + (v[6] + v[7]));
      tot += __shfl_xor(tot, 32);
      if (lane < 32) op[(size_t)(bblk + bl) * 384 + ht * 32 + lane] = tot;
    }
  };

  layer(IC<4>{}, IC<64>{}, Wf0, X0T + (size_t)bblk * (16 * 64),
        bias0, outp + 0, Xa);
  __syncthreads();   // publish X1 before L1 af reads
  layer(IC<8>{}, IC<XROW>{}, Wf1, Xa, bias1, outp + 128, Xb);
  __syncthreads();   // publish X2 before L2 af reads
  layer(IC<8>{}, IC<XROW>{}, Wf2, Xb, bias2, outp + 256,
        (unsigned short*)nullptr);
}

extern "C" void kernel_launch(void* const* d_in, const int* in_sizes, int n_in,
                              void* d_out, int out_size, void* d_ws, size_t ws_size,
                              hipStream_t stream) {
  (void)in_sizes; (void)n_in; (void)out_size; (void)ws_size;
  const float* X0g = (const float*)d_in[0];
  const float* W0  = (const float*)d_in[1];
  const float* b0  = (const float*)d_in[2];
  const float* W1  = (const float*)d_in[3];
  const float* b1  = (const float*)d_in[4];
  const float* W2  = (const float*)d_in[5];
  const float* b2  = (const float*)d_in[6];
  float* out = (float*)d_out;

  char* p = (char*)d_ws;
  unsigned short* X0T = (unsigned short*)p; p += (size_t)NB_B * 16 * 64 * 2;
  float*          X0f = (float*)p;          p += (size_t)NB_B * NB_F0 * 16 * 4;
  unsigned short* Wf0 = (unsigned short*)p; p += (size_t)NB_F0 * 4 * 4 * 512 * 2;
  unsigned short* Wf1 = (unsigned short*)p; p += (size_t)NB_F0 * 4 * 8 * 512 * 2;
  unsigned short* Wf2 = (unsigned short*)p; p += (size_t)NB_F0 * 4 * 8 * 512 * 2;

  constexpr int TW0  = NB_F0 * 4 * 4 * 512;
  constexpr int TW12 = NB_F0 * 4 * 8 * 512;
  const int prep_blocks = NB_B + TW0 / 256 + 2 * (TW12 / 256);
  hipLaunchKernelGGL(prep_all_kernel, dim3(prep_blocks), dim3(256), 0, stream,
                     X0g, X0T, X0f, W0, Wf0, W1, Wf1, W2, Wf2);

  hipLaunchKernelGGL(cin_fused, dim3(NB_B / 4), dim3(512), 0, stream,
                     Wf0, Wf1, Wf2, X0T, X0f, b0, b1, b2, out);
}

// Round 13
// 326.158 us; speedup vs baseline: 1.0064x; 1.0064x over previous
//
#include <hip/hip_runtime.h>
#include <stdint.h>

// CIN layers: Xn[b,h,d] = sum_{j,k} W[h,j,k] * X0[b,j,d] * Xi[b,k,d] + bias[h]
// y[d,h] = sum_k Xi*W (mfma_32x32x16, A rows m=b'*16+d, B cols=32h), then
// Xacc += x0[b,j,d]*y.
// R22 post-mortem: 512-thr block capped VGPR at 128 (like (256,2)) -> W
// ping-pong demoted, serial vmcnt per stage, fused 235->278. Geometry
// reverted to R21 (best, 296.5 total). TLP is not the lever.
// R23: T15 pipelined merge. R21's per-stage {8-MFMA chain -> xsc/fma merge}
// serializes MFMA-pipe and VALU-pipe per wave (merge waits full chain).
// Now carry y1p (prev stage's P1 chain result): each stage does
//   {ds_reads for pending merge -> chain(s,P0) -> merge P1(s-1) ->
//    chain(s,P1) -> merge P0(s)}
// so every merge hides in the shadow of 8 freshly-issued independent MFMAs
// and every x0 ds_read issues a chain ahead of use. Numerically identical
// (same per-accumulator addition order). +16 VGPR (y1p); ~215 total under
// the 256 cap of launch_bounds(256,1). Spill alarm = WRITE_SIZE.
// Everything else = R21: fused 3 layers, Xn via LDS (XROW=130, 0 conflicts),
// f32 x0 factors, j-major, W global->reg ping-pong, merged single prep.

#define NB_F0 39
#define NB_H  128
#define NB_B  4096
#define XROW 130   // padded k-row stride (shorts) for Xa/Xb

typedef float f32x4  __attribute__((ext_vector_type(4)));
typedef float f32x16 __attribute__((ext_vector_type(16)));
typedef short s16x8  __attribute__((ext_vector_type(8)));

template <int N> struct IC { static constexpr int value = N; };

__device__ __forceinline__ unsigned short rne_bf16(float f) {
  union { float f; unsigned u; } v; v.f = f;
  return (unsigned short)((v.u + 0x7fffu + ((v.u >> 16) & 1u)) >> 16);
}

// Merged prep (one launch):
//  blocks [0, NB_B): X0 f32 [B][39][16] -> X0T bf16 [B][16][64] (k=j pad) and
//    X0f f32 [B][39][16] d-PERMUTED (pos<->d swap bits 2,3) so a lane's 8 x0
//    factors for MFMA regs r=0..7 (d=(r&3)+8*((r>>2)&1)+4L) are contiguous.
//  remaining blocks: W f32 [128][39*Fi] -> Wf bf16 fragment-linear:
//    Wf[(((j*4+t)*KC16+c)*64+lane)*8+i] = W[h=t*32+(lane&31)][j, k=c*16+
//    (lane>>5)*8+i] (0 if k>=Fi), for W0 (KC16=4) then W1, W2 (KC16=8).
__global__ void prep_all_kernel(const float* __restrict__ X0g,
                                unsigned short* __restrict__ X0T,
                                float* __restrict__ X0f,
                                const float* __restrict__ W0s,
                                unsigned short* __restrict__ Wf0,
                                const float* __restrict__ W1s,
                                unsigned short* __restrict__ Wf1,
                                const float* __restrict__ W2s,
                                unsigned short* __restrict__ Wf2) {
  const int t = threadIdx.x;
  int blk = blockIdx.x;
  if (blk < NB_B) {
    const int b = blk;
    {
      const int d  = t >> 4;
      const int k4 = (t & 15) << 2;
      unsigned short vv[4];
#pragma unroll
      for (int i = 0; i < 4; ++i) {
        const int k = k4 + i;
        vv[i] = (k < NB_F0)
                    ? rne_bf16(X0g[(size_t)b * (NB_F0 * 16) + k * 16 + d])
                    : (unsigned short)0;
      }
      ushort4 pk; pk.x = vv[0]; pk.y = vv[1]; pk.z = vv[2]; pk.w = vv[3];
      *(ushort4*)&X0T[((size_t)b * 16 + d) * 64 + k4] = pk;
    }
    for (int idx = t; idx < NB_F0 * 16; idx += 256) {
      const int j = idx >> 4, pos = idx & 15;
      const int d =
          (pos & 3) | (((pos >> 3) & 1) << 2) | (((pos >> 2) & 1) << 3);
      X0f[(size_t)b * (NB_F0 * 16) + idx] =
          X0g[(size_t)b * (NB_F0 * 16) + j * 16 + d];
    }
    return;
  }
  blk -= NB_B;
  constexpr int TW0  = NB_F0 * 4 * 4 * 512;   // KC16=4
  constexpr int TW12 = NB_F0 * 4 * 8 * 512;   // KC16=8
  constexpr int NB0  = TW0 / 256;
  constexpr int NB12 = TW12 / 256;
  const float* Wsrc; unsigned short* Wdst; int Fi, kshift, idx;
  if (blk < NB0) {
    Wsrc = W0s; Wdst = Wf0; Fi = 39;  kshift = 2; idx = blk * 256 + t;
  } else if (blk < NB0 + NB12) {
    Wsrc = W1s; Wdst = Wf1; Fi = 128; kshift = 3;
    idx = (blk - NB0) * 256 + t;
  } else {
    Wsrc = W2s; Wdst = Wf2; Fi = 128; kshift = 3;
    idx = (blk - NB0 - NB12) * 256 + t;
  }
  const int i    = idx & 7;
  const int lane = (idx >> 3) & 63;
  const int c    = (idx >> 9) & ((1 << kshift) - 1);
  const int jt   = idx >> (9 + kshift);
  const int tt   = jt & 3;
  const int j    = jt >> 2;
  const int h = tt * 32 + (lane & 31);
  const int k = c * 16 + ((lane >> 5) << 3) + i;
  unsigned short v = 0;
  if (k < Fi) v = rne_bf16(Wsrc[(size_t)h * (NB_F0 * Fi) + j * Fi + k]);
  Wdst[idx] = v;
}

__global__ __launch_bounds__(256, 1) void cin_fused(
    const unsigned short* __restrict__ Wf0,
    const unsigned short* __restrict__ Wf1,
    const unsigned short* __restrict__ Wf2,
    const unsigned short* __restrict__ X0T,  // [B][16][64] bf16 (k zero-pad)
    const float* __restrict__ X0f,           // [B][39][16] f32, d-permuted
    const float* __restrict__ bias0,
    const float* __restrict__ bias1,
    const float* __restrict__ bias2,
    float* __restrict__ outp)                // [B][384]
{
  __shared__ __attribute__((aligned(16))) float x0f[4 * NB_F0 * 16];
  __shared__ __attribute__((aligned(16))) unsigned short Xa[4 * 16 * XROW];
  __shared__ __attribute__((aligned(16))) unsigned short Xb[4 * 16 * XROW];

  const int tid  = threadIdx.x;
  const int lane = tid & 63;
  const int wv   = tid >> 6;        // h-tile: h = wv*32 + col
  const int L    = lane >> 5;       // k-half selector within a 16-chunk
  const int col  = lane & 31;       // A row m / B col
  const int bblk = blockIdx.x * 4;  // 4 b per block

  // ---- stage x0 factors (f32 d-permuted, flat coalesced copy) ----
  {
    const float* src = X0f + (size_t)bblk * (NB_F0 * 16);
    for (int c = tid; c < (4 * NB_F0 * 16) / 4; c += 256)
      *(f32x4*)&x0f[c * 4] = *(const f32x4*)&src[c * 4];
  }
  __syncthreads();   // publish x0f

  const int x0base = L * 8;   // all waves share the block's 4 b (broadcast)

  // One CIN layer. KC16 = K-chunks (4 for Fi=64-pad, 8 for Fi=128);
  // AST = Xi A-fragment row stride in shorts (64 global X0T, XROW LDS).
  auto layer = [&](auto kc, auto ast, const unsigned short* __restrict__ Wl,
                   const unsigned short* af_base, const float* __restrict__ bv,
                   float* __restrict__ op, unsigned short* xn) {
    constexpr int KC16 = decltype(kc)::value;
    constexpr int AST  = decltype(ast)::value;

    // ---- Xi A-fragments: chain P covers b_local = 2P + (col>>4) ----
    s16x8 af[2][KC16];
#pragma unroll
    for (int P = 0; P < 2; ++P) {
      const unsigned short* base = af_base +
          (size_t)(2 * P + (col >> 4)) * (16 * AST) + (col & 15) * AST + L * 8;
#pragma unroll
      for (int c = 0; c < KC16; ++c) af[P][c] = *(const s16x8*)(base + c * 16);
    }

    f32x16 Xacc[2], kZero;
#pragma unroll
    for (int r = 0; r < 16; ++r) kZero[r] = 0.f;
#pragma unroll
    for (int P = 0; P < 2; ++P) Xacc[P] = kZero;

    // ---- W fragments straight from global (L2-hot) into registers ----
    const s16x8* __restrict__ W8 = (const s16x8*)Wl;
    auto wload = [&](int j, s16x8 (&w)[KC16]) {
      const s16x8* p = W8 + ((size_t)(j * 4 + wv) * KC16) * 64 + lane;
#pragma unroll
      for (int c = 0; c < KC16; ++c) w[c] = p[c * 64];
    };

    // 8-MFMA dependent chain for (stage s, chain P) on W regs w.
    auto chainP0 = [&](const s16x8 (&w)[KC16]) -> f32x16 {
      f32x16 y = __builtin_amdgcn_mfma_f32_32x32x16_bf16(af[0][0], w[0],
                                                         kZero, 0, 0, 0);
#pragma unroll
      for (int c = 1; c < KC16; ++c)
        y = __builtin_amdgcn_mfma_f32_32x32x16_bf16(af[0][c], w[c], y, 0, 0, 0);
      return y;
    };
    auto chainP1 = [&](const s16x8 (&w)[KC16]) -> f32x16 {
      f32x16 y = __builtin_amdgcn_mfma_f32_32x32x16_bf16(af[1][0], w[0],
                                                         kZero, 0, 0, 0);
#pragma unroll
      for (int c = 1; c < KC16; ++c)
        y = __builtin_amdgcn_mfma_f32_32x32x16_bf16(af[1][c], w[c], y, 0, 0, 0);
      return y;
    };

    // x0-scale merge for (stage s, chain P): Xacc[P] += xsc * y.
    auto merge = [&](int s, int P, const f32x16& y) {
      const float* xr0 = &x0f[x0base + (2 * P + 0) * (NB_F0 * 16) + s * 16];
      const float* xr1 = &x0f[x0base + (2 * P + 1) * (NB_F0 * 16) + s * 16];
      const f32x4 a0 = *(const f32x4*)(xr0);
      const f32x4 a1 = *(const f32x4*)(xr0 + 4);
      const f32x4 a2 = *(const f32x4*)(xr1);
      const f32x4 a3 = *(const f32x4*)(xr1 + 4);
      f32x16 xsc;
#pragma unroll
      for (int i = 0; i < 4; ++i) {
        xsc[i]      = a0[i];
        xsc[4 + i]  = a1[i];
        xsc[8 + i]  = a2[i];
        xsc[12 + i] = a3[i];
      }
      Xacc[P] = __builtin_elementwise_fma(xsc, y, Xacc[P]);
    };

    // T15 pipelined stage: merge(s-1,P1) hides under chain(s,P0);
    // merge(s,P0) hides under chain(s,P1). y1p carries P1 across stages.
    f32x16 y1p;
    auto stage_body = [&](int s, const s16x8 (&w)[KC16]) {
      f32x16 y0 = chainP0(w);     // 8 MFMAs issued
      merge(s - 1, 1, y1p);       // VALU in chain-P0's shadow
      f32x16 y1 = chainP1(w);     // 8 MFMAs issued
      merge(s, 0, y0);            // VALU in chain-P1's shadow
      y1p = y1;
    };

    // ---- barrier-free main loop: W reg ping-pong, 1-stage prefetch ----
    s16x8 wA[KC16], wB[KC16];
    wload(0, wA);
    wload(1, wB);
    {   // peel s=0 (no pending merge yet)
      f32x16 y0 = chainP0(wA);
      f32x16 y1 = chainP1(wA);
      merge(0, 0, y0);
      y1p = y1;
      wload(2, wA);
    }
    for (int s = 1; s + 1 < NB_F0; s += 2) {
      stage_body(s, wB);
      wload(s + 2 < NB_F0 ? s + 2 : 0, wB);   // reissue post-use (reg WAR ok)
      stage_body(s + 1, wA);
      wload(s + 3 < NB_F0 ? s + 3 : 0, wA);
    }
    // S=39: peel(0) + pairs (1,2)..(37,38) cover all stages.
    merge(NB_F0 - 1, 1, y1p);   // final pending merge

    // ---- epilogue: sums to global; Xn to LDS in A-fragment layout ----
    const float bias_v = bv[wv * 32 + col];
#pragma unroll
    for (int P = 0; P < 2; ++P) {
#pragma unroll
      for (int bh = 0; bh < 2; ++bh) {
        const int bl = 2 * P + bh;
        float v[8];
#pragma unroll
        for (int m = 0; m < 8; ++m) v[m] = Xacc[P][bh * 8 + m] + bias_v;
        if (xn) {
#pragma unroll
          for (int m = 0; m < 8; ++m) {
            const int d = (m & 3) + 8 * ((m >> 2) & 1) + 4 * L;
            xn[(bl * 16 + d) * XROW + wv * 32 + col] = rne_bf16(v[m]);
          }
        }
        float tot = ((v[0] + v[1]) + (v[2] + v[3])) +
                    ((v[4] + v[5]) + (v[6] + v[7]));
        tot += __shfl_xor(tot, 32);
        if (lane < 32) op[(size_t)(bblk + bl) * 384 + wv * 32 + lane] = tot;
      }
    }
  };

  layer(IC<4>{}, IC<64>{}, Wf0, X0T + (size_t)bblk * (16 * 64),
        bias0, outp + 0, Xa);
  __syncthreads();   // publish X1 before L1 af reads
  layer(IC<8>{}, IC<XROW>{}, Wf1, Xa, bias1, outp + 128, Xb);
  __syncthreads();   // publish X2 before L2 af reads
  layer(IC<8>{}, IC<XROW>{}, Wf2, Xb, bias2, outp + 256,
        (unsigned short*)nullptr);
}

extern "C" void kernel_launch(void* const* d_in, const int* in_sizes, int n_in,
                              void* d_out, int out_size, void* d_ws, size_t ws_size,
                              hipStream_t stream) {
  (void)in_sizes; (void)n_in; (void)out_size; (void)ws_size;
  const float* X0g = (const float*)d_in[0];
  const float* W0  = (const float*)d_in[1];
  const float* b0  = (const float*)d_in[2];
  const float* W1  = (const float*)d_in[3];
  const float* b1  = (const float*)d_in[4];
  const float* W2  = (const float*)d_in[5];
  const float* b2  = (const float*)d_in[6];
  float* out = (float*)d_out;

  char* p = (char*)d_ws;
  unsigned short* X0T = (unsigned short*)p; p += (size_t)NB_B * 16 * 64 * 2;
  float*          X0f = (float*)p;          p += (size_t)NB_B * NB_F0 * 16 * 4;
  unsigned short* Wf0 = (unsigned short*)p; p += (size_t)NB_F0 * 4 * 4 * 512 * 2;
  unsigned short* Wf1 = (unsigned short*)p; p += (size_t)NB_F0 * 4 * 8 * 512 * 2;
  unsigned short* Wf2 = (unsigned short*)p; p += (size_t)NB_F0 * 4 * 8 * 512 * 2;

  constexpr int TW0  = NB_F0 * 4 * 4 * 512;
  constexpr int TW12 = NB_F0 * 4 * 8 * 512;
  const int prep_blocks = NB_B + TW0 / 256 + 2 * (TW12 / 256);
  hipLaunchKernelGGL(prep_all_kernel, dim3(prep_blocks), dim3(256), 0, stream,
                     X0g, X0T, X0f, W0, Wf0, W1, Wf1, W2, Wf2);

  hipLaunchKernelGGL(cin_fused, dim3(NB_B / 4), dim3(256), 0, stream,
                     Wf0, Wf1, Wf2, X0T, X0f, b0, b1, b2, out);
}

// Round 14
// 309.671 us; speedup vs baseline: 1.0599x; 1.0532x over previous
//
#include <hip/hip_runtime.h>
#include <stdint.h>

// CIN layers: Xn[b,h,d] = sum_{j,k} W[h,j,k] * X0[b,j,d] * Xi[b,k,d] + bias[h]
// y[d,h] = sum_k Xi*W (mfma_32x32x16, A rows m=b'*16+d, B cols=32h), then
// Xacc += x0[b,j,d]*y.
// R23 post-mortem: manual T15 interleave regressed (273us, MfmaUtil 34) --
// compiler's R21 schedule beats hand-pinned order (lesson #5). R21 = best.
// R21 accounting: per-stage wall ~300cy = MFMA 128 + VALU ~80 + LDS ~96:
// per-wave pipes SUM at 1 wave/SIMD. R22's 2-wave try is confounded: demand
// ~150 > 128 cap -> W ping-pong demoted -> vmcnt serialization.
// R24: K-SPLIT ACROSS WAVE PAIRS. Block = 512 thr = 8 waves = 4 ht x 2
// K-halves, 4 b. Per-wave: af 32 + w 32 + Xacc 32 ~ 120 regs -> fits the
// 128 cap CLEANLY (no demotion). Main loop = R21 verbatim, chains now
// 4-deep (2x independent starts). Layer-end: kh=1 publishes partial Xacc
// via dead-buffer LDS scratch (L0->Xb, L1/L2->Xa; 2 rounds of 16KB, bank-
// free layout), kh=0 sums + runs the unchanged epilogue. Residency: VGPR
// 128 -> 16 waves/CU; LDS 43.3KB -> 2 blocks/CU -> 4 waves/SIMD from
// independent blocks. W L2 traffic per block unchanged.

#define NB_F0 39
#define NB_H  128
#define NB_B  4096
#define XROW 130   // padded k-row stride (shorts) for Xa/Xb

typedef float f32x4  __attribute__((ext_vector_type(4)));
typedef float f32x16 __attribute__((ext_vector_type(16)));
typedef short s16x8  __attribute__((ext_vector_type(8)));

template <int N> struct IC { static constexpr int value = N; };

__device__ __forceinline__ unsigned short rne_bf16(float f) {
  union { float f; unsigned u; } v; v.f = f;
  return (unsigned short)((v.u + 0x7fffu + ((v.u >> 16) & 1u)) >> 16);
}

// Merged prep (one launch):
//  blocks [0, NB_B): X0 f32 [B][39][16] -> X0T bf16 [B][16][64] (k=j pad) and
//    X0f f32 [B][39][16] d-PERMUTED (pos<->d swap bits 2,3) so a lane's 8 x0
//    factors for MFMA regs r=0..7 (d=(r&3)+8*((r>>2)&1)+4L) are contiguous.
//  remaining blocks: W f32 [128][39*Fi] -> Wf bf16 fragment-linear:
//    Wf[(((j*4+t)*KC16+c)*64+lane)*8+i] = W[h=t*32+(lane&31)][j, k=c*16+
//    (lane>>5)*8+i] (0 if k>=Fi), for W0 (KC16=4) then W1, W2 (KC16=8).
__global__ void prep_all_kernel(const float* __restrict__ X0g,
                                unsigned short* __restrict__ X0T,
                                float* __restrict__ X0f,
                                const float* __restrict__ W0s,
                                unsigned short* __restrict__ Wf0,
                                const float* __restrict__ W1s,
                                unsigned short* __restrict__ Wf1,
                                const float* __restrict__ W2s,
                                unsigned short* __restrict__ Wf2) {
  const int t = threadIdx.x;
  int blk = blockIdx.x;
  if (blk < NB_B) {
    const int b = blk;
    {
      const int d  = t >> 4;
      const int k4 = (t & 15) << 2;
      unsigned short vv[4];
#pragma unroll
      for (int i = 0; i < 4; ++i) {
        const int k = k4 + i;
        vv[i] = (k < NB_F0)
                    ? rne_bf16(X0g[(size_t)b * (NB_F0 * 16) + k * 16 + d])
                    : (unsigned short)0;
      }
      ushort4 pk; pk.x = vv[0]; pk.y = vv[1]; pk.z = vv[2]; pk.w = vv[3];
      *(ushort4*)&X0T[((size_t)b * 16 + d) * 64 + k4] = pk;
    }
    for (int idx = t; idx < NB_F0 * 16; idx += 256) {
      const int j = idx >> 4, pos = idx & 15;
      const int d =
          (pos & 3) | (((pos >> 3) & 1) << 2) | (((pos >> 2) & 1) << 3);
      X0f[(size_t)b * (NB_F0 * 16) + idx] =
          X0g[(size_t)b * (NB_F0 * 16) + j * 16 + d];
    }
    return;
  }
  blk -= NB_B;
  constexpr int TW0  = NB_F0 * 4 * 4 * 512;   // KC16=4
  constexpr int TW12 = NB_F0 * 4 * 8 * 512;   // KC16=8
  constexpr int NB0  = TW0 / 256;
  constexpr int NB12 = TW12 / 256;
  const float* Wsrc; unsigned short* Wdst; int Fi, kshift, idx;
  if (blk < NB0) {
    Wsrc = W0s; Wdst = Wf0; Fi = 39;  kshift = 2; idx = blk * 256 + t;
  } else if (blk < NB0 + NB12) {
    Wsrc = W1s; Wdst = Wf1; Fi = 128; kshift = 3;
    idx = (blk - NB0) * 256 + t;
  } else {
    Wsrc = W2s; Wdst = Wf2; Fi = 128; kshift = 3;
    idx = (blk - NB0 - NB12) * 256 + t;
  }
  const int i    = idx & 7;
  const int lane = (idx >> 3) & 63;
  const int c    = (idx >> 9) & ((1 << kshift) - 1);
  const int jt   = idx >> (9 + kshift);
  const int tt   = jt & 3;
  const int j    = jt >> 2;
  const int h = tt * 32 + (lane & 31);
  const int k = c * 16 + ((lane >> 5) << 3) + i;
  unsigned short v = 0;
  if (k < Fi) v = rne_bf16(Wsrc[(size_t)h * (NB_F0 * Fi) + j * Fi + k]);
  Wdst[idx] = v;
}

__global__ __launch_bounds__(512, 1) void cin_fused(
    const unsigned short* __restrict__ Wf0,
    const unsigned short* __restrict__ Wf1,
    const unsigned short* __restrict__ Wf2,
    const unsigned short* __restrict__ X0T,  // [B][16][64] bf16 (k zero-pad)
    const float* __restrict__ X0f,           // [B][39][16] f32, d-permuted
    const float* __restrict__ bias0,
    const float* __restrict__ bias1,
    const float* __restrict__ bias2,
    float* __restrict__ outp)                // [B][384]
{
  __shared__ __attribute__((aligned(16))) float x0f[4 * NB_F0 * 16];
  __shared__ __attribute__((aligned(16))) unsigned short Xa[4 * 16 * XROW];
  __shared__ __attribute__((aligned(16))) unsigned short Xb[4 * 16 * XROW];

  const int tid  = threadIdx.x;
  const int lane = tid & 63;
  const int wv   = tid >> 6;        // 0..7
  const int ht   = wv & 3;          // h-tile: h = ht*32 + col
  const int kh   = wv >> 2;         // K-half owned by this wave
  const int L    = lane >> 5;       // k-half selector within a 16-chunk
  const int col  = lane & 31;       // A row m / B col
  const int bblk = blockIdx.x * 4;  // 4 b per block

  // ---- stage x0 factors (f32 d-permuted, flat coalesced copy) ----
  {
    const float* src = X0f + (size_t)bblk * (NB_F0 * 16);
    for (int c = tid; c < (4 * NB_F0 * 16) / 4; c += 512)
      *(f32x4*)&x0f[c * 4] = *(const f32x4*)&src[c * 4];
  }
  __syncthreads();   // publish x0f

  const int x0base = L * 8;   // all waves share the block's 4 b (broadcast)

  // One CIN layer. KC16 = total K-chunks (4 for Fi=64-pad, 8 for Fi=128);
  // this wave handles KCh = KC16/2 chunks [kh*KCh, kh*KCh+KCh).
  // AST = Xi A-fragment row stride in shorts (64 global X0T, XROW LDS).
  // redsc: 16KB f32 scratch (dead LDS buffer) for the kh partial reduction.
  auto layer = [&](auto kc, auto ast, const unsigned short* __restrict__ Wl,
                   const unsigned short* af_base, const float* __restrict__ bv,
                   float* __restrict__ op, unsigned short* xn,
                   float* redsc, bool afbar) {
    constexpr int KC16 = decltype(kc)::value;
    constexpr int KCh  = KC16 / 2;
    constexpr int AST  = decltype(ast)::value;

    // ---- Xi A-fragments for this wave's K-half; chain P: b'=2P+(col>>4) ----
    s16x8 af[2][KCh];
#pragma unroll
    for (int P = 0; P < 2; ++P) {
      const unsigned short* base = af_base +
          (size_t)(2 * P + (col >> 4)) * (16 * AST) + (col & 15) * AST +
          kh * (KCh * 16) + L * 8;
#pragma unroll
      for (int c = 0; c < KCh; ++c) af[P][c] = *(const s16x8*)(base + c * 16);
    }
    if (afbar) __syncthreads();   // af source doubles as reduction scratch

    f32x16 Xacc[2], kZero;
#pragma unroll
    for (int r = 0; r < 16; ++r) kZero[r] = 0.f;
#pragma unroll
    for (int P = 0; P < 2; ++P) Xacc[P] = kZero;

    // ---- W fragments straight from global (L2-hot) into registers ----
    const s16x8* __restrict__ W8 = (const s16x8*)Wl;
    auto wload = [&](int j, s16x8 (&w)[KCh]) {
      const s16x8* p =
          W8 + ((size_t)(j * 4 + ht) * KC16 + kh * KCh) * 64 + lane;
#pragma unroll
      for (int c = 0; c < KCh; ++c) w[c] = p[c * 64];
    };

    auto compute = [&](int s, const s16x8 (&w)[KCh]) {
#pragma unroll
      for (int P = 0; P < 2; ++P) {
        f32x16 y = __builtin_amdgcn_mfma_f32_32x32x16_bf16(af[P][0], w[0],
                                                           kZero, 0, 0, 0);
#pragma unroll
        for (int c = 1; c < KCh; ++c)
          y = __builtin_amdgcn_mfma_f32_32x32x16_bf16(af[P][c], w[c], y,
                                                      0, 0, 0);
        // x0 scale: regs 0-7 <- b'=2P (this lane's L 8-run), 8-15 <- 2P+1.
        const float* xr0 = &x0f[x0base + (2 * P + 0) * (NB_F0 * 16) + s * 16];
        const float* xr1 = &x0f[x0base + (2 * P + 1) * (NB_F0 * 16) + s * 16];
        const f32x4 a0 = *(const f32x4*)(xr0);
        const f32x4 a1 = *(const f32x4*)(xr0 + 4);
        const f32x4 a2 = *(const f32x4*)(xr1);
        const f32x4 a3 = *(const f32x4*)(xr1 + 4);
        f32x16 xsc;
#pragma unroll
        for (int i = 0; i < 4; ++i) {
          xsc[i]      = a0[i];
          xsc[4 + i]  = a1[i];
          xsc[8 + i]  = a2[i];
          xsc[12 + i] = a3[i];
        }
        Xacc[P] = __builtin_elementwise_fma(xsc, y, Xacc[P]);
      }
    };

    // ---- barrier-free main loop: W reg ping-pong, 1-stage prefetch ----
    s16x8 wA[KCh], wB[KCh];
    wload(0, wA);
    wload(1, wB);
    int s = 0;
    for (; s + 2 <= NB_F0; s += 2) {
      compute(s, wA);
      wload(s + 2 < NB_F0 ? s + 2 : 0, wA);   // reissue post-use (reg WAR ok)
      compute(s + 1, wB);
      if (s + 3 < NB_F0) wload(s + 3, wB);
    }
    if (s < NB_F0) compute(s, wA);   // odd tail (S=39)

    // ---- K-half reduction through LDS scratch (bank-free: stride 64) ----
#pragma unroll
    for (int P = 0; P < 2; ++P) {
      if (kh == 1) {
#pragma unroll
        for (int r = 0; r < 16; ++r)
          redsc[(ht * 16 + r) * 64 + lane] = Xacc[P][r];
      }
      __syncthreads();
      if (kh == 0) {
#pragma unroll
        for (int r = 0; r < 16; ++r)
          Xacc[P][r] += redsc[(ht * 16 + r) * 64 + lane];
      }
      __syncthreads();
    }

    // ---- epilogue (kh=0 waves): sums to global; Xn to LDS ----
    if (kh == 0) {
      const float bias_v = bv[ht * 32 + col];
#pragma unroll
      for (int P = 0; P < 2; ++P) {
#pragma unroll
        for (int bh = 0; bh < 2; ++bh) {
          const int bl = 2 * P + bh;
          float v[8];
#pragma unroll
          for (int m = 0; m < 8; ++m) v[m] = Xacc[P][bh * 8 + m] + bias_v;
          if (xn) {
#pragma unroll
            for (int m = 0; m < 8; ++m) {
              const int d = (m & 3) + 8 * ((m >> 2) & 1) + 4 * L;
              xn[(bl * 16 + d) * XROW + ht * 32 + col] = rne_bf16(v[m]);
            }
          }
          float tot = ((v[0] + v[1]) + (v[2] + v[3])) +
                      ((v[4] + v[5]) + (v[6] + v[7]));
          tot += __shfl_xor(tot, 32);
          if (lane < 32)
            op[(size_t)(bblk + bl) * 384 + ht * 32 + lane] = tot;
        }
      }
    }
  };

  // L0: af from global X0T (AST=64); scratch = Xb (untouched); no afbar.
  layer(IC<4>{}, IC<64>{}, Wf0, X0T + (size_t)bblk * (16 * 64),
        bias0, outp + 0, Xa, (float*)Xb, false);
  __syncthreads();   // publish X1 (Xa) before L1 af reads
  // L1: af from Xa; scratch = Xa (dead after af loads -> afbar).
  layer(IC<8>{}, IC<XROW>{}, Wf1, Xa, bias1, outp + 128, Xb,
        (float*)Xa, true);
  __syncthreads();   // publish X2 (Xb) before L2 af reads
  // L2: af from Xb; scratch = Xa (dead since L1); no Xn.
  layer(IC<8>{}, IC<XROW>{}, Wf2, Xb, bias2, outp + 256,
        (unsigned short*)nullptr, (float*)Xa, false);
}

extern "C" void kernel_launch(void* const* d_in, const int* in_sizes, int n_in,
                              void* d_out, int out_size, void* d_ws, size_t ws_size,
                              hipStream_t stream) {
  (void)in_sizes; (void)n_in; (void)out_size; (void)ws_size;
  const float* X0g = (const float*)d_in[0];
  const float* W0  = (const float*)d_in[1];
  const float* b0  = (const float*)d_in[2];
  const float* W1  = (const float*)d_in[3];
  const float* b1  = (const float*)d_in[4];
  const float* W2  = (const float*)d_in[5];
  const float* b2  = (const float*)d_in[6];
  float* out = (float*)d_out;

  char* p = (char*)d_ws;
  unsigned short* X0T = (unsigned short*)p; p += (size_t)NB_B * 16 * 64 * 2;
  float*          X0f = (float*)p;          p += (size_t)NB_B * NB_F0 * 16 * 4;
  unsigned short* Wf0 = (unsigned short*)p; p += (size_t)NB_F0 * 4 * 4 * 512 * 2;
  unsigned short* Wf1 = (unsigned short*)p; p += (size_t)NB_F0 * 4 * 8 * 512 * 2;
  unsigned short* Wf2 = (unsigned short*)p; p += (size_t)NB_F0 * 4 * 8 * 512 * 2;

  constexpr int TW0  = NB_F0 * 4 * 4 * 512;
  constexpr int TW12 = NB_F0 * 4 * 8 * 512;
  const int prep_blocks = NB_B + TW0 / 256 + 2 * (TW12 / 256);
  hipLaunchKernelGGL(prep_all_kernel, dim3(prep_blocks), dim3(256), 0, stream,
                     X0g, X0T, X0f, W0, Wf0, W1, Wf1, W2, Wf2);

  hipLaunchKernelGGL(cin_fused, dim3(NB_B / 4), dim3(512), 0, stream,
                     Wf0, Wf1, Wf2, X0T, X0f, b0, b1, b2, out);
}

// Round 15
// 281.056 us; speedup vs baseline: 1.1678x; 1.1018x over previous
//
#include <hip/hip_runtime.h>
#include <stdint.h>

// CIN layers: Xn[b,h,d] = sum_{j,k} W[h,j,k] * X0[b,j,d] * Xi[b,k,d] + bias[h]
// y[d,h] = sum_k Xi*W (mfma_32x32x16, A rows m=b'*16+d, B cols=32h), then
// Xacc += x0[b,j,d]*y.
// R24 post-mortem: K-split gave clean regs (128) + 2x occupancy (22%) and
// STILL lost to R21 (254 vs 235): duplicated per-wave merge work ate the
// latency-filling gain. 14-round verdict: scheduling/TLP/ILP restructures
// are neutral-to-negative; only WORK-VOLUME cuts win. R21 = best (296.5).
// R25 = R21 + two non-structural cuts:
// (a) L0 at K=48 (KC16=3): layer-0 contraction is 39-wide; 48 >= 39 so the
//     4th chunk was pure zero-pad. L0 MFMA chain 4->3, W-loads -25%
//     (~5us of issue time). X0T re-laid [B][16][48]; Wf0 KC16=3 (/3 index
//     in prep). Numerically identical.
// (b) T5 s_setprio(1) around each MFMA chain: R21's barrier-free loop lets
//     the 4 waves drift out of phase -- the role-diversity precondition T5
//     needs (null only on lockstep structures). Free if neutral.
// Everything else = R21: fused 3 layers, Xn via LDS (XROW=130, 0 conflicts),
// f32 x0 factors, j-major, W global->reg ping-pong, merged single prep,
// launch_bounds(256,1).

#define NB_F0 39
#define NB_H  128
#define NB_B  4096
#define XROW 130   // padded k-row stride (shorts) for Xa/Xb

typedef float f32x4  __attribute__((ext_vector_type(4)));
typedef float f32x16 __attribute__((ext_vector_type(16)));
typedef short s16x8  __attribute__((ext_vector_type(8)));

template <int N> struct IC { static constexpr int value = N; };

__device__ __forceinline__ unsigned short rne_bf16(float f) {
  union { float f; unsigned u; } v; v.f = f;
  return (unsigned short)((v.u + 0x7fffu + ((v.u >> 16) & 1u)) >> 16);
}

// Merged prep (one launch):
//  blocks [0, NB_B): X0 f32 [B][39][16] -> X0T bf16 [B][16][48] (k=j, zero-
//    padded 39->48, layer-0 A source) and X0f f32 [B][39][16] d-PERMUTED
//    (pos<->d swap bits 2,3) so a lane's 8 x0 factors for MFMA regs r=0..7
//    (d=(r&3)+8*((r>>2)&1)+4L) are contiguous.
//  remaining blocks: W f32 [128][39*Fi] -> Wf bf16 fragment-linear:
//    Wf[(((j*4+t)*KC16+c)*64+lane)*8+i] = W[h=t*32+(lane&31)][j, k=c*16+
//    (lane>>5)*8+i] (0 if k>=Fi): W0 (KC16=3, /3 index), W1/W2 (KC16=8).
__global__ void prep_all_kernel(const float* __restrict__ X0g,
                                unsigned short* __restrict__ X0T,
                                float* __restrict__ X0f,
                                const float* __restrict__ W0s,
                                unsigned short* __restrict__ Wf0,
                                const float* __restrict__ W1s,
                                unsigned short* __restrict__ Wf1,
                                const float* __restrict__ W2s,
                                unsigned short* __restrict__ Wf2) {
  const int t = threadIdx.x;
  int blk = blockIdx.x;
  if (blk < NB_B) {
    const int b = blk;
    {
      const int d  = t >> 4;
      const int kq = t & 15;
      if (kq < 12) {                    // 48 k in ushort4 chunks
        const int k4 = kq << 2;
        unsigned short vv[4];
#pragma unroll
        for (int i = 0; i < 4; ++i) {
          const int k = k4 + i;
          vv[i] = (k < NB_F0)
                      ? rne_bf16(X0g[(size_t)b * (NB_F0 * 16) + k * 16 + d])
                      : (unsigned short)0;
        }
        ushort4 pk; pk.x = vv[0]; pk.y = vv[1]; pk.z = vv[2]; pk.w = vv[3];
        *(ushort4*)&X0T[((size_t)b * 16 + d) * 48 + k4] = pk;
      }
    }
    for (int idx = t; idx < NB_F0 * 16; idx += 256) {
      const int j = idx >> 4, pos = idx & 15;
      const int d =
          (pos & 3) | (((pos >> 3) & 1) << 2) | (((pos >> 2) & 1) << 3);
      X0f[(size_t)b * (NB_F0 * 16) + idx] =
          X0g[(size_t)b * (NB_F0 * 16) + j * 16 + d];
    }
    return;
  }
  blk -= NB_B;
  constexpr int TW0  = NB_F0 * 4 * 3 * 512;   // KC16=3
  constexpr int TW12 = NB_F0 * 4 * 8 * 512;   // KC16=8
  constexpr int NB0  = TW0 / 256;
  constexpr int NB12 = TW12 / 256;
  if (blk < NB0) {
    const int idx  = blk * 256 + t;
    const int i    = idx & 7;
    const int lane = (idx >> 3) & 63;
    const int rest = idx >> 9;
    const int c    = rest % 3;
    const int jt   = rest / 3;
    const int tt   = jt & 3;
    const int j    = jt >> 2;
    const int h = tt * 32 + (lane & 31);
    const int k = c * 16 + ((lane >> 5) << 3) + i;
    unsigned short v = 0;
    if (k < NB_F0) v = rne_bf16(W0s[(size_t)h * (NB_F0 * NB_F0) + j * NB_F0 + k]);
    Wf0[idx] = v;
    return;
  }
  blk -= NB0;
  const float* Wsrc; unsigned short* Wdst; int idx;
  if (blk < NB12) { Wsrc = W1s; Wdst = Wf1; idx = blk * 256 + t; }
  else            { Wsrc = W2s; Wdst = Wf2; idx = (blk - NB12) * 256 + t; }
  const int i    = idx & 7;
  const int lane = (idx >> 3) & 63;
  const int c    = (idx >> 9) & 7;
  const int jt   = idx >> 12;
  const int tt   = jt & 3;
  const int j    = jt >> 2;
  const int h = tt * 32 + (lane & 31);
  const int k = c * 16 + ((lane >> 5) << 3) + i;
  Wdst[idx] = rne_bf16(Wsrc[(size_t)h * (NB_F0 * 128) + j * 128 + k]);
}

__global__ __launch_bounds__(256, 1) void cin_fused(
    const unsigned short* __restrict__ Wf0,
    const unsigned short* __restrict__ Wf1,
    const unsigned short* __restrict__ Wf2,
    const unsigned short* __restrict__ X0T,  // [B][16][48] bf16 (k zero-pad)
    const float* __restrict__ X0f,           // [B][39][16] f32, d-permuted
    const float* __restrict__ bias0,
    const float* __restrict__ bias1,
    const float* __restrict__ bias2,
    float* __restrict__ outp)                // [B][384]
{
  __shared__ __attribute__((aligned(16))) float x0f[4 * NB_F0 * 16];
  __shared__ __attribute__((aligned(16))) unsigned short Xa[4 * 16 * XROW];
  __shared__ __attribute__((aligned(16))) unsigned short Xb[4 * 16 * XROW];

  const int tid  = threadIdx.x;
  const int lane = tid & 63;
  const int wv   = tid >> 6;        // h-tile: h = wv*32 + col
  const int L    = lane >> 5;       // k-half selector within a 16-chunk
  const int col  = lane & 31;       // A row m / B col
  const int bblk = blockIdx.x * 4;  // 4 b per block

  // ---- stage x0 factors (f32 d-permuted, flat coalesced copy) ----
  {
    const float* src = X0f + (size_t)bblk * (NB_F0 * 16);
    for (int c = tid; c < (4 * NB_F0 * 16) / 4; c += 256)
      *(f32x4*)&x0f[c * 4] = *(const f32x4*)&src[c * 4];
  }
  __syncthreads();   // publish x0f

  const int x0base = L * 8;   // all waves share the block's 4 b (broadcast)

  // One CIN layer. KC16 = K-chunks (3 for L0's 48-pad, 8 for Fi=128);
  // AST = Xi A-fragment row stride in shorts (48 global X0T, XROW LDS).
  auto layer = [&](auto kc, auto ast, const unsigned short* __restrict__ Wl,
                   const unsigned short* af_base, const float* __restrict__ bv,
                   float* __restrict__ op, unsigned short* xn) {
    constexpr int KC16 = decltype(kc)::value;
    constexpr int AST  = decltype(ast)::value;

    // ---- Xi A-fragments: chain P covers b_local = 2P + (col>>4) ----
    s16x8 af[2][KC16];
#pragma unroll
    for (int P = 0; P < 2; ++P) {
      const unsigned short* base = af_base +
          (size_t)(2 * P + (col >> 4)) * (16 * AST) + (col & 15) * AST + L * 8;
#pragma unroll
      for (int c = 0; c < KC16; ++c) af[P][c] = *(const s16x8*)(base + c * 16);
    }

    f32x16 Xacc[2], kZero;
#pragma unroll
    for (int r = 0; r < 16; ++r) kZero[r] = 0.f;
#pragma unroll
    for (int P = 0; P < 2; ++P) Xacc[P] = kZero;

    // ---- W fragments straight from global (L2-hot) into registers ----
    const s16x8* __restrict__ W8 = (const s16x8*)Wl;
    auto wload = [&](int j, s16x8 (&w)[KC16]) {
      const s16x8* p = W8 + ((size_t)(j * 4 + wv) * KC16) * 64 + lane;
#pragma unroll
      for (int c = 0; c < KC16; ++c) w[c] = p[c * 64];
    };

    auto compute = [&](int s, const s16x8 (&w)[KC16]) {
#pragma unroll
      for (int P = 0; P < 2; ++P) {
        __builtin_amdgcn_s_setprio(1);          // T5: favor MFMA cluster
        f32x16 y = __builtin_amdgcn_mfma_f32_32x32x16_bf16(af[P][0], w[0],
                                                           kZero, 0, 0, 0);
#pragma unroll
        for (int c = 1; c < KC16; ++c)
          y = __builtin_amdgcn_mfma_f32_32x32x16_bf16(af[P][c], w[c], y,
                                                      0, 0, 0);
        __builtin_amdgcn_s_setprio(0);
        // x0 scale: regs 0-7 <- b'=2P (this lane's L 8-run), 8-15 <- 2P+1.
        // f32 factors: broadcast ds_read_b128 x4, zero unpack VALU.
        const float* xr0 = &x0f[x0base + (2 * P + 0) * (NB_F0 * 16) + s * 16];
        const float* xr1 = &x0f[x0base + (2 * P + 1) * (NB_F0 * 16) + s * 16];
        const f32x4 a0 = *(const f32x4*)(xr0);
        const f32x4 a1 = *(const f32x4*)(xr0 + 4);
        const f32x4 a2 = *(const f32x4*)(xr1);
        const f32x4 a3 = *(const f32x4*)(xr1 + 4);
        f32x16 xsc;
#pragma unroll
        for (int i = 0; i < 4; ++i) {
          xsc[i]      = a0[i];
          xsc[4 + i]  = a1[i];
          xsc[8 + i]  = a2[i];
          xsc[12 + i] = a3[i];
        }
        Xacc[P] = __builtin_elementwise_fma(xsc, y, Xacc[P]);
      }
    };

    // ---- barrier-free main loop: W reg ping-pong, 1-stage prefetch ----
    s16x8 wA[KC16], wB[KC16];
    wload(0, wA);
    wload(1, wB);
    int s = 0;
    for (; s + 2 <= NB_F0; s += 2) {
      compute(s, wA);
      wload(s + 2 < NB_F0 ? s + 2 : 0, wA);   // reissue post-use (reg WAR ok)
      compute(s + 1, wB);
      if (s + 3 < NB_F0) wload(s + 3, wB);
    }
    if (s < NB_F0) compute(s, wA);   // odd tail (S=39)

    // ---- epilogue: sums to global; Xn to LDS in A-fragment layout ----
    const float bias_v = bv[wv * 32 + col];
#pragma unroll
    for (int P = 0; P < 2; ++P) {
#pragma unroll
      for (int bh = 0; bh < 2; ++bh) {
        const int bl = 2 * P + bh;
        float v[8];
#pragma unroll
        for (int m = 0; m < 8; ++m) v[m] = Xacc[P][bh * 8 + m] + bias_v;
        if (xn) {
#pragma unroll
          for (int m = 0; m < 8; ++m) {
            const int d = (m & 3) + 8 * ((m >> 2) & 1) + 4 * L;
            xn[(bl * 16 + d) * XROW + wv * 32 + col] = rne_bf16(v[m]);
          }
        }
        float tot = ((v[0] + v[1]) + (v[2] + v[3])) +
                    ((v[4] + v[5]) + (v[6] + v[7]));
        tot += __shfl_xor(tot, 32);
        if (lane < 32) op[(size_t)(bblk + bl) * 384 + wv * 32 + lane] = tot;
      }
    }
  };

  layer(IC<3>{}, IC<48>{}, Wf0, X0T + (size_t)bblk * (16 * 48),
        bias0, outp + 0, Xa);
  __syncthreads();   // publish X1 before L1 af reads
  layer(IC<8>{}, IC<XROW>{}, Wf1, Xa, bias1, outp + 128, Xb);
  __syncthreads();   // publish X2 before L2 af reads
  layer(IC<8>{}, IC<XROW>{}, Wf2, Xb, bias2, outp + 256,
        (unsigned short*)nullptr);
}

extern "C" void kernel_launch(void* const* d_in, const int* in_sizes, int n_in,
                              void* d_out, int out_size, void* d_ws, size_t ws_size,
                              hipStream_t stream) {
  (void)in_sizes; (void)n_in; (void)out_size; (void)ws_size;
  const float* X0g = (const float*)d_in[0];
  const float* W0  = (const float*)d_in[1];
  const float* b0  = (const float*)d_in[2];
  const float* W1  = (const float*)d_in[3];
  const float* b1  = (const float*)d_in[4];
  const float* W2  = (const float*)d_in[5];
  const float* b2  = (const float*)d_in[6];
  float* out = (float*)d_out;

  char* p = (char*)d_ws;
  unsigned short* X0T = (unsigned short*)p; p += (size_t)NB_B * 16 * 48 * 2;
  float*          X0f = (float*)p;          p += (size_t)NB_B * NB_F0 * 16 * 4;
  unsigned short* Wf0 = (unsigned short*)p; p += (size_t)NB_F0 * 4 * 3 * 512 * 2;
  unsigned short* Wf1 = (unsigned short*)p; p += (size_t)NB_F0 * 4 * 8 * 512 * 2;
  unsigned short* Wf2 = (unsigned short*)p; p += (size_t)NB_F0 * 4 * 8 * 512 * 2;

  constexpr int TW0  = NB_F0 * 4 * 3 * 512;
  constexpr int TW12 = NB_F0 * 4 * 8 * 512;
  const int prep_blocks = NB_B + TW0 / 256 + 2 * (TW12 / 256);
  hipLaunchKernelGGL(prep_all_kernel, dim3(prep_blocks), dim3(256), 0, stream,
                     X0g, X0T, X0f, W0, Wf0, W1, Wf1, W2, Wf2);

  hipLaunchKernelGGL(cin_fused, dim3(NB_B / 4), dim3(256), 0, stream,
                     Wf0, Wf1, Wf2, X0T, X0f, b0, b1, b2, out);
}